// Round 1
// baseline (1618.373 us; speedup 1.0000x reference)
//
#include <hip/hip_runtime.h>
#include <cstdint>
#include <math.h>

#define T_TOK 8192
#define DM 1024
#define DFF 4096
#define NE 8

typedef __attribute__((ext_vector_type(8))) short short8;
typedef __attribute__((ext_vector_type(4))) float f32x4;

static __device__ __forceinline__ unsigned short f2bf(float f) {
    union { float f; unsigned int u; } v; v.f = f;
    unsigned int r = (v.u + 0x7FFFu + ((v.u >> 16) & 1u)) >> 16;
    return (unsigned short)r;
}

// ---------------- Router: logits, softmax, top-2, lists, importance ----------------
__global__ __launch_bounds__(256) void router_kernel(
    const float* __restrict__ x, const float* __restrict__ gw,
    int* __restrict__ counts, float* __restrict__ imp,
    int* __restrict__ ptok, float* __restrict__ pw)
{
    __shared__ float4 sgw[NE * 256];
    __shared__ float simp[NE];
    const int tid = threadIdx.x;
    #pragma unroll
    for (int j = 0; j < 8; ++j) sgw[tid + j * 256] = ((const float4*)gw)[tid + j * 256];
    if (tid < NE) simp[tid] = 0.f;
    __syncthreads();

    const int wid = tid >> 6, lane = tid & 63;
    const int t = blockIdx.x * 4 + wid;
    float acc[NE];
    #pragma unroll
    for (int e = 0; e < NE; ++e) acc[e] = 0.f;
    const float4* xr = (const float4*)(x + (size_t)t * DM);
    #pragma unroll
    for (int j = 0; j < 4; ++j) {
        int idx = lane + j * 64;
        float4 xv = xr[idx];
        #pragma unroll
        for (int e = 0; e < NE; ++e) {
            float4 g = sgw[e * 256 + idx];
            acc[e] += xv.x * g.x + xv.y * g.y + xv.z * g.z + xv.w * g.w;
        }
    }
    #pragma unroll
    for (int off = 32; off; off >>= 1) {
        #pragma unroll
        for (int e = 0; e < NE; ++e) acc[e] += __shfl_xor(acc[e], off);
    }
    if (lane == 0) {
        float m = acc[0];
        #pragma unroll
        for (int e = 1; e < NE; ++e) m = fmaxf(m, acc[e]);
        float p[NE], s = 0.f;
        #pragma unroll
        for (int e = 0; e < NE; ++e) { p[e] = expf(acc[e] - m); s += p[e]; }
        float inv = 1.f / s;
        #pragma unroll
        for (int e = 0; e < NE; ++e) { p[e] *= inv; atomicAdd(&simp[e], p[e]); }
        int i0 = 0;
        #pragma unroll
        for (int e = 1; e < NE; ++e) if (p[e] > p[i0]) i0 = e;
        int i1 = (i0 == 0) ? 1 : 0;
        #pragma unroll
        for (int e = 0; e < NE; ++e) if (e != i0 && p[e] > p[i1]) i1 = e;
        float v0 = p[i0], v1 = p[i1], wsum = v0 + v1;
        int s0 = atomicAdd(&counts[i0], 1);
        ptok[i0 * T_TOK + s0] = t; pw[i0 * T_TOK + s0] = v0 / wsum;
        int s1 = atomicAdd(&counts[i1], 1);
        ptok[i1 * T_TOK + s1] = t; pw[i1 * T_TOK + s1] = v1 / wsum;
    }
    __syncthreads();
    if (tid < NE) atomicAdd(&imp[tid], simp[tid]);
}

// ---------------- Finalize: offsets prefix + aux loss ----------------
__global__ void finalize_kernel(const int* __restrict__ counts,
                                const float* __restrict__ imp,
                                int* __restrict__ offs, float* __restrict__ aux_out)
{
    if (threadIdx.x == 0 && blockIdx.x == 0) {
        int o = 0; float aux = 0.f;
        for (int e = 0; e < NE; ++e) {
            offs[e] = o; o += counts[e];
            aux += (imp[e] / (float)T_TOK) * ((float)counts[e] / (float)(T_TOK * 2));
        }
        offs[NE] = o;
        *aux_out = (float)NE * aux;
    }
}

// ---------------- Grouped GEMM (B^T form), 128x128 tile, BK=64, bf16 MFMA ----------------
// EPI==0: H[pair, f_local] = gelu(gather(x) @ w1[e]^T + b1)   (K = 1024, N = FFC chunk)
// EPI==1: out[tok, d]     += w_pair * (H @ w2[e]^T + b2)      (K = FFC chunk, N = 1024)
template<int EPI>
__global__ __launch_bounds__(256) void gemm_bt(
    const float* __restrict__ x, const unsigned short* __restrict__ Hin,
    unsigned short* __restrict__ Hout,
    const float* __restrict__ W, const float* __restrict__ bias,
    const int* __restrict__ counts, const int* __restrict__ offs,
    const int* __restrict__ ptok, const float* __restrict__ pw,
    float* __restrict__ out, int FFC, int cch)
{
    const int e = blockIdx.z;
    const int n_e = counts[e];
    const int m0 = blockIdx.x * 128;
    if (m0 >= n_e) return;
    const int nt = blockIdx.y;
    const int KD = (EPI == 0) ? DM : FFC;

    __shared__ unsigned short lA[128 * 72];
    __shared__ unsigned short lB[128 * 72];

    const int tid = threadIdx.x, wid = tid >> 6, lane = tid & 63;
    const int msub = (wid & 1) * 64, nsub = (wid >> 1) * 64;
    const int hbase = offs[e];

    f32x4 acc[4][4];
    #pragma unroll
    for (int i = 0; i < 4; ++i)
        #pragma unroll
        for (int j = 0; j < 4; ++j) acc[i][j] = (f32x4)0.f;

    for (int k0 = 0; k0 < KD; k0 += 64) {
        // ---- stage A tile [128 x 64] into LDS as bf16 ----
        if (EPI == 0) {
            #pragma unroll
            for (int j = 0; j < 8; ++j) {
                int li = tid + j * 256;
                int r = li >> 4, s4 = li & 15;
                int m = m0 + r;
                int tok = ptok[e * T_TOK + (m < n_e ? m : 0)];
                const float4 v = *(const float4*)(x + (size_t)tok * DM + k0 + s4 * 4);
                uint2 u;
                u.x = (unsigned)f2bf(v.x) | ((unsigned)f2bf(v.y) << 16);
                u.y = (unsigned)f2bf(v.z) | ((unsigned)f2bf(v.w) << 16);
                *(uint2*)(&lA[r * 72 + s4 * 4]) = u;
            }
        } else {
            #pragma unroll
            for (int j = 0; j < 4; ++j) {
                int li = tid + j * 256;
                int r = li >> 3, s8 = li & 7;
                int m = m0 + r;
                int row = hbase + (m < n_e ? m : 0);
                short8 v = *(const short8*)(Hin + (size_t)row * FFC + k0 + s8 * 8);
                *(short8*)(&lA[r * 72 + s8 * 8]) = v;
            }
        }
        // ---- stage B tile [128 x 64] (weights, fp32 -> bf16) ----
        #pragma unroll
        for (int j = 0; j < 8; ++j) {
            int li = tid + j * 256;
            int r = li >> 4, s4 = li & 15;
            size_t boff;
            if (EPI == 0)
                boff = ((size_t)e * DFF + (size_t)cch * FFC + nt * 128 + r) * DM + k0 + s4 * 4;
            else
                boff = ((size_t)e * DM + nt * 128 + r) * DFF + (size_t)cch * FFC + k0 + s4 * 4;
            const float4 v = *(const float4*)(W + boff);
            uint2 u;
            u.x = (unsigned)f2bf(v.x) | ((unsigned)f2bf(v.y) << 16);
            u.y = (unsigned)f2bf(v.z) | ((unsigned)f2bf(v.w) << 16);
            *(uint2*)(&lB[r * 72 + s4 * 4]) = u;
        }
        __syncthreads();
        #pragma unroll
        for (int kk = 0; kk < 2; ++kk) {
            short8 af[4], bf[4];
            #pragma unroll
            for (int i = 0; i < 4; ++i) {
                af[i] = *(const short8*)(&lA[(msub + i * 16 + (lane & 15)) * 72 + kk * 32 + (lane >> 4) * 8]);
                bf[i] = *(const short8*)(&lB[(nsub + i * 16 + (lane & 15)) * 72 + kk * 32 + (lane >> 4) * 8]);
            }
            #pragma unroll
            for (int mi = 0; mi < 4; ++mi)
                #pragma unroll
                for (int nj = 0; nj < 4; ++nj)
                    acc[mi][nj] = __builtin_amdgcn_mfma_f32_16x16x32_bf16(af[mi], bf[nj], acc[mi][nj], 0, 0, 0);
        }
        __syncthreads();
    }

    // ---- epilogue ----
    const int rbase = (lane >> 4) * 4, cidx = lane & 15;
    if (EPI == 0) {
        #pragma unroll
        for (int mi = 0; mi < 4; ++mi) {
            #pragma unroll
            for (int r = 0; r < 4; ++r) {
                int m = m0 + msub + mi * 16 + rbase + r;
                if (m >= n_e) continue;
                size_t hrow = (size_t)(hbase + m) * FFC;
                #pragma unroll
                for (int nj = 0; nj < 4; ++nj) {
                    int f = nt * 128 + nsub + nj * 16 + cidx;
                    float v = acc[mi][nj][r] + bias[e * DFF + cch * FFC + f];
                    float g = 0.5f * v * (1.f + erff(v * 0.70710678118654752f));
                    Hout[hrow + f] = f2bf(g);
                }
            }
        }
    } else {
        #pragma unroll
        for (int mi = 0; mi < 4; ++mi) {
            #pragma unroll
            for (int r = 0; r < 4; ++r) {
                int m = m0 + msub + mi * 16 + rbase + r;
                if (m >= n_e) continue;
                int pidx = e * T_TOK + m;
                int tok = ptok[pidx];
                float wgt = pw[pidx];
                float* orow = out + (size_t)tok * DM;
                #pragma unroll
                for (int nj = 0; nj < 4; ++nj) {
                    int d = nt * 128 + nsub + nj * 16 + cidx;
                    float v = acc[mi][nj][r];
                    if (cch == 0) v += bias[e * DM + d];
                    atomicAdd(&orow[d], wgt * v);
                }
            }
        }
    }
}

extern "C" void kernel_launch(void* const* d_in, const int* in_sizes, int n_in,
                              void* d_out, int out_size, void* d_ws, size_t ws_size,
                              hipStream_t stream)
{
    const float* x  = (const float*)d_in[0];
    const float* gw = (const float*)d_in[1];
    const float* w1 = (const float*)d_in[2];
    const float* b1 = (const float*)d_in[3];
    const float* w2 = (const float*)d_in[4];
    const float* b2 = (const float*)d_in[5];
    float* out = (float*)d_out;

    char* ws = (char*)d_ws;
    int*   counts = (int*)ws;                       // 8 ints
    float* imp    = (float*)(ws + 64);              // 8 floats
    int*   offs   = (int*)(ws + 128);               // 9 ints
    int*   ptok   = (int*)(ws + 256);               // NE*T ints
    float* pw     = (float*)(ws + 256 + (size_t)NE * T_TOK * 4);
    size_t fixed  = 256 + (size_t)NE * T_TOK * 4 * 2;
    unsigned short* H = (unsigned short*)(ws + ((fixed + 511) & ~(size_t)511));
    size_t havail = (ws_size > fixed + 1024) ? (ws_size - fixed - 1024) : 0;

    int FFC = 0;
    for (int f = DFF; f >= 128; f >>= 1) {
        if ((size_t)(2 * T_TOK) * (size_t)f * 2 <= havail) { FFC = f; break; }
    }
    if (FFC == 0) return;  // workspace too small — will show as incorrect, informing next round

    hipMemsetAsync(ws, 0, 256, stream);
    hipMemsetAsync(d_out, 0, (size_t)out_size * 4, stream);

    router_kernel<<<T_TOK / 4, 256, 0, stream>>>(x, gw, counts, imp, ptok, pw);
    finalize_kernel<<<1, 64, 0, stream>>>(counts, imp, offs, out + (size_t)out_size - 1);

    const int NCH = DFF / FFC;
    for (int c = 0; c < NCH; ++c) {
        dim3 g1(T_TOK / 128, FFC / 128, NE);
        gemm_bt<0><<<g1, 256, 0, stream>>>(x, H, H, w1, b1, counts, offs, ptok, pw, out, FFC, c);
        dim3 g2(T_TOK / 128, DM / 128, NE);
        gemm_bt<1><<<g2, 256, 0, stream>>>(x, H, H, w2, b2, counts, offs, ptok, pw, out, FFC, c);
    }
}

// Round 2
// 1468.298 us; speedup vs baseline: 1.1022x; 1.1022x over previous
//
#include <hip/hip_runtime.h>
#include <cstdint>
#include <math.h>

#define T_TOK 8192
#define DM 1024
#define DFF 4096
#define NE 8

typedef __attribute__((ext_vector_type(8))) short short8;
typedef __attribute__((ext_vector_type(4))) float f32x4;

#define GLDS16(g, l) __builtin_amdgcn_global_load_lds( \
    (const __attribute__((address_space(1))) void*)(g), \
    (__attribute__((address_space(3))) void*)(l), 16, 0, 0)

static __device__ __forceinline__ unsigned short f2bf(float f) {
    union { float f; unsigned int u; } v; v.f = f;
    unsigned int r = (v.u + 0x7FFFu + ((v.u >> 16) & 1u)) >> 16;
    return (unsigned short)r;
}

// ---------------- fp32 -> bf16 converters ----------------
__global__ __launch_bounds__(256) void conv_flat(const float* __restrict__ src,
                                                 unsigned short* __restrict__ dst,
                                                 long long n)
{
    long long i = ((long long)blockIdx.x * 256 + threadIdx.x) * 4;
    if (i >= n) return;
    const float4 v = *(const float4*)(src + i);
    uint2 u;
    u.x = (unsigned)f2bf(v.x) | ((unsigned)f2bf(v.y) << 16);
    u.y = (unsigned)f2bf(v.z) | ((unsigned)f2bf(v.w) << 16);
    *(uint2*)(dst + i) = u;
}

// strided rows: dst[row][0..ncols) = bf16(src[src_off + row*src_stride + 0..ncols))
__global__ __launch_bounds__(256) void conv_rows(const float* __restrict__ src,
                                                 unsigned short* __restrict__ dst,
                                                 long long src_off, long long src_stride,
                                                 int ncols)
{
    long long row = blockIdx.y;
    int c = (blockIdx.x * 256 + threadIdx.x) * 4;
    if (c >= ncols) return;
    const float4 v = *(const float4*)(src + src_off + row * src_stride + c);
    uint2 u;
    u.x = (unsigned)f2bf(v.x) | ((unsigned)f2bf(v.y) << 16);
    u.y = (unsigned)f2bf(v.z) | ((unsigned)f2bf(v.w) << 16);
    *(uint2*)(dst + row * (long long)ncols + c) = u;
}

// ---------------- Router ----------------
__global__ __launch_bounds__(256) void router_kernel(
    const float* __restrict__ x, const float* __restrict__ gw,
    int* __restrict__ counts, float* __restrict__ imp,
    int* __restrict__ ptok, float* __restrict__ pw)
{
    __shared__ float4 sgw[NE * 256];
    __shared__ float simp[NE];
    const int tid = threadIdx.x;
    #pragma unroll
    for (int j = 0; j < 8; ++j) sgw[tid + j * 256] = ((const float4*)gw)[tid + j * 256];
    if (tid < NE) simp[tid] = 0.f;
    __syncthreads();

    const int wid = tid >> 6, lane = tid & 63;
    const int t = blockIdx.x * 4 + wid;
    float acc[NE];
    #pragma unroll
    for (int e = 0; e < NE; ++e) acc[e] = 0.f;
    const float4* xr = (const float4*)(x + (size_t)t * DM);
    #pragma unroll
    for (int j = 0; j < 4; ++j) {
        int idx = lane + j * 64;
        float4 xv = xr[idx];
        #pragma unroll
        for (int e = 0; e < NE; ++e) {
            float4 g = sgw[e * 256 + idx];
            acc[e] += xv.x * g.x + xv.y * g.y + xv.z * g.z + xv.w * g.w;
        }
    }
    #pragma unroll
    for (int off = 32; off; off >>= 1) {
        #pragma unroll
        for (int e = 0; e < NE; ++e) acc[e] += __shfl_xor(acc[e], off);
    }
    if (lane == 0) {
        float m = acc[0];
        #pragma unroll
        for (int e = 1; e < NE; ++e) m = fmaxf(m, acc[e]);
        float p[NE], s = 0.f;
        #pragma unroll
        for (int e = 0; e < NE; ++e) { p[e] = expf(acc[e] - m); s += p[e]; }
        float inv = 1.f / s;
        #pragma unroll
        for (int e = 0; e < NE; ++e) { p[e] *= inv; atomicAdd(&simp[e], p[e]); }
        int i0 = 0;
        #pragma unroll
        for (int e = 1; e < NE; ++e) if (p[e] > p[i0]) i0 = e;
        int i1 = (i0 == 0) ? 1 : 0;
        #pragma unroll
        for (int e = 0; e < NE; ++e) if (e != i0 && p[e] > p[i1]) i1 = e;
        float v0 = p[i0], v1 = p[i1], wsum = v0 + v1;
        int s0 = atomicAdd(&counts[i0], 1);
        ptok[i0 * T_TOK + s0] = t; pw[i0 * T_TOK + s0] = v0 / wsum;
        int s1 = atomicAdd(&counts[i1], 1);
        ptok[i1 * T_TOK + s1] = t; pw[i1 * T_TOK + s1] = v1 / wsum;
    }
    __syncthreads();
    if (tid < NE) atomicAdd(&imp[tid], simp[tid]);
}

__global__ void finalize_kernel(const int* __restrict__ counts,
                                const float* __restrict__ imp,
                                int* __restrict__ offs, float* __restrict__ aux_out)
{
    if (threadIdx.x == 0 && blockIdx.x == 0) {
        int o = 0; float aux = 0.f;
        for (int e = 0; e < NE; ++e) {
            offs[e] = o; o += counts[e];
            aux += (imp[e] / (float)T_TOK) * ((float)counts[e] / (float)(T_TOK * 2));
        }
        offs[NE] = o;
        *aux_out = (float)NE * aux;
    }
}

// ---------------- Grouped GEMM (B^T), m97 structure: 128x128, BK=64, global_load_lds ----------------
// EPI==0: H[pair, f] = gelu(gather(xb) @ w1b[e]^T + b1)   (K = DM,  N = FFC chunk)
// EPI==1: out[tok,d] += w_pair * (H @ w2b[e]^T + b2)      (K = FFC, N = DM)
template<int EPI>
__global__ __launch_bounds__(256) void gemm_bt(
    const unsigned short* __restrict__ A,   // EPI0: xb [T][DM]; EPI1: H [2T][FFC]
    const unsigned short* __restrict__ W,   // bf16 weights
    const float* __restrict__ bias,
    const int* __restrict__ counts, const int* __restrict__ offs,
    const int* __restrict__ ptok, const float* __restrict__ pw,
    unsigned short* __restrict__ Hout, float* __restrict__ out,
    int FFC, int cch, int wfull)
{
    const int e = blockIdx.z;
    const int n_e = counts[e];
    const int m0 = blockIdx.x * 128;
    if (m0 >= n_e) return;
    const int nt = blockIdx.y;
    const int KD = (EPI == 0) ? DM : FFC;
    const int hbase = offs[e];

    __shared__ unsigned short lA[128 * 64];
    __shared__ unsigned short lB[128 * 64];

    const int tid = threadIdx.x, lane = tid & 63, wid = tid >> 6;
    const int msub = (wid & 1) * 64, nsub = (wid >> 1) * 64;

    // weight-row addressing (full-converted vs per-chunk-converted layouts)
    int wrow0; long long wstride, wcol0;
    if (EPI == 0) {
        wrow0 = e * (wfull ? DFF : FFC) + (wfull ? cch * FFC : 0) + nt * 128;
        wstride = DM; wcol0 = 0;
    } else {
        wrow0 = e * DM + nt * 128;
        wstride = (wfull ? DFF : FFC); wcol0 = (wfull ? (long long)cch * FFC : 0);
    }

    // precompute per-thread global addresses for the 4 A- and 4 B- staging issues
    const unsigned short* aaddr[4];
    const unsigned short* baddr[4];
    #pragma unroll
    for (int j = 0; j < 4; ++j) {
        int li = tid + j * 256;
        int r = li >> 3, s = (li & 7) * 8;
        long long arow;
        if (EPI == 0) {
            int m = m0 + r;
            int tok = ptok[e * T_TOK + (m < n_e ? m : 0)];
            arow = (long long)tok * DM;
        } else {
            int m = m0 + r;
            arow = (long long)(hbase + (m < n_e ? m : 0)) * FFC;
        }
        aaddr[j] = A + arow + s;
        baddr[j] = W + (long long)(wrow0 + r) * wstride + wcol0 + s;
    }

    f32x4 acc[4][4];
    #pragma unroll
    for (int i = 0; i < 4; ++i)
        #pragma unroll
        for (int j = 0; j < 4; ++j) acc[i][j] = (f32x4)0.f;

    for (int k0 = 0; k0 < KD; k0 += 64) {
        #pragma unroll
        for (int j = 0; j < 4; ++j) {
            GLDS16(aaddr[j], &lA[(tid + j * 256) * 8]);
            aaddr[j] += 64;
        }
        #pragma unroll
        for (int j = 0; j < 4; ++j) {
            GLDS16(baddr[j], &lB[(tid + j * 256) * 8]);
            baddr[j] += 64;
        }
        __syncthreads();
        #pragma unroll
        for (int kk = 0; kk < 2; ++kk) {
            short8 af[4], bf[4];
            #pragma unroll
            for (int i = 0; i < 4; ++i) {
                af[i] = *(const short8*)(&lA[(msub + i * 16 + (lane & 15)) * 64 + kk * 32 + (lane >> 4) * 8]);
                bf[i] = *(const short8*)(&lB[(nsub + i * 16 + (lane & 15)) * 64 + kk * 32 + (lane >> 4) * 8]);
            }
            #pragma unroll
            for (int mi = 0; mi < 4; ++mi)
                #pragma unroll
                for (int nj = 0; nj < 4; ++nj)
                    acc[mi][nj] = __builtin_amdgcn_mfma_f32_16x16x32_bf16(af[mi], bf[nj], acc[mi][nj], 0, 0, 0);
        }
        __syncthreads();
    }

    const int rbase = (lane >> 4) * 4, cidx = lane & 15;
    if (EPI == 0) {
        #pragma unroll
        for (int mi = 0; mi < 4; ++mi) {
            #pragma unroll
            for (int r = 0; r < 4; ++r) {
                int m = m0 + msub + mi * 16 + rbase + r;
                if (m >= n_e) continue;
                long long hrow = (long long)(hbase + m) * FFC;
                #pragma unroll
                for (int nj = 0; nj < 4; ++nj) {
                    int f = nt * 128 + nsub + nj * 16 + cidx;
                    float v = acc[mi][nj][r] + bias[e * DFF + cch * FFC + f];
                    float g = 0.5f * v * (1.f + erff(v * 0.70710678118654752f));
                    Hout[hrow + f] = f2bf(g);
                }
            }
        }
    } else {
        #pragma unroll
        for (int mi = 0; mi < 4; ++mi) {
            #pragma unroll
            for (int r = 0; r < 4; ++r) {
                int m = m0 + msub + mi * 16 + rbase + r;
                if (m >= n_e) continue;
                int pidx = e * T_TOK + m;
                int tok = ptok[pidx];
                float wgt = pw[pidx];
                float* orow = out + (long long)tok * DM;
                #pragma unroll
                for (int nj = 0; nj < 4; ++nj) {
                    int d = nt * 128 + nsub + nj * 16 + cidx;
                    float v = acc[mi][nj][r];
                    if (cch == 0) v += bias[e * DM + d];
                    atomicAdd(&orow[d], wgt * v);
                }
            }
        }
    }
}

extern "C" void kernel_launch(void* const* d_in, const int* in_sizes, int n_in,
                              void* d_out, int out_size, void* d_ws, size_t ws_size,
                              hipStream_t stream)
{
    const float* x  = (const float*)d_in[0];
    const float* gw = (const float*)d_in[1];
    const float* w1 = (const float*)d_in[2];
    const float* b1 = (const float*)d_in[3];
    const float* w2 = (const float*)d_in[4];
    const float* b2 = (const float*)d_in[5];
    float* out = (float*)d_out;

    char* ws = (char*)d_ws;
    int*   counts = (int*)ws;
    float* imp    = (float*)(ws + 64);
    int*   offs   = (int*)(ws + 128);
    int*   ptok   = (int*)(ws + 256);
    float* pw     = (float*)(ws + 256 + (size_t)NE * T_TOK * 4);
    size_t cur = 256 + (size_t)NE * T_TOK * 8;
    cur = (cur + 511) & ~(size_t)511;

    unsigned short* xb = (unsigned short*)(ws + cur);
    cur += (size_t)T_TOK * DM * 2;                       // 16.8 MB

    const size_t wfull_bytes = (size_t)NE * DFF * DM * 2; // 67.1 MB each
    const size_t hrow_total  = 2 * (size_t)T_TOK;         // 16384 pair-rows

    // Plan A: fully converted weights + H chunk
    int FFC = 0, wfull = 0;
    unsigned short *w1b = nullptr, *w2b = nullptr, *H = nullptr;
    for (int f = DFF; f >= 512; f >>= 1) {
        size_t need = cur + 2 * wfull_bytes + hrow_total * (size_t)f * 2;
        if (need <= ws_size) { FFC = f; wfull = 1; break; }
    }
    if (wfull) {
        w1b = (unsigned short*)(ws + cur); cur += wfull_bytes;
        w2b = (unsigned short*)(ws + cur); cur += wfull_bytes;
        H   = (unsigned short*)(ws + cur);
    } else {
        // Plan B: per-chunk converted weights
        for (int f = 1024; f >= 128; f >>= 1) {
            size_t wc = (size_t)NE * f * DM * 2;
            size_t need = cur + 2 * wc + hrow_total * (size_t)f * 2;
            if (need <= ws_size) { FFC = f; break; }
        }
        if (FFC == 0) return;
        size_t wc = (size_t)NE * FFC * DM * 2;
        w1b = (unsigned short*)(ws + cur); cur += wc;
        w2b = (unsigned short*)(ws + cur); cur += wc;
        H   = (unsigned short*)(ws + cur);
    }

    hipMemsetAsync(ws, 0, 256, stream);
    hipMemsetAsync(d_out, 0, (size_t)out_size * 4, stream);

    router_kernel<<<T_TOK / 4, 256, 0, stream>>>(x, gw, counts, imp, ptok, pw);
    finalize_kernel<<<1, 64, 0, stream>>>(counts, imp, offs, out + (size_t)out_size - 1);

    // x -> bf16
    {
        long long n = (long long)T_TOK * DM;
        conv_flat<<<(unsigned)(n / 1024), 256, 0, stream>>>(x, xb, n);
    }
    if (wfull) {
        long long n = (long long)NE * DFF * DM;
        conv_flat<<<(unsigned)(n / 1024), 256, 0, stream>>>(w1, w1b, n);
        conv_flat<<<(unsigned)(n / 1024), 256, 0, stream>>>(w2, w2b, n);
    }

    const int NCH = DFF / FFC;
    for (int c = 0; c < NCH; ++c) {
        if (!wfull) {
            // w1 chunk: per expert contiguous slice [e][c*FFC..)(FFC rows of DM)
            dim3 gc1((unsigned)((long long)FFC * DM / 1024), NE);
            conv_rows<<<gc1, 256, 0, stream>>>(w1, w1b,
                (long long)c * FFC * DM, (long long)DFF * DM, FFC * DM);
            // w2 chunk: rows = NE*DM, each row FFC cols at offset c*FFC, stride DFF
            dim3 gc2((unsigned)((FFC + 1023) / 1024), NE * DM);
            conv_rows<<<gc2, 256, 0, stream>>>(w2, w2b,
                (long long)c * FFC, (long long)DFF, FFC);
        }
        dim3 g1(T_TOK / 128, FFC / 128, NE);
        gemm_bt<0><<<g1, 256, 0, stream>>>(xb, w1b, b1, counts, offs, ptok, pw, H, out, FFC, c, wfull);
        dim3 g2(T_TOK / 128, DM / 128, NE);
        gemm_bt<1><<<g2, 256, 0, stream>>>(H, w2b, b2, counts, offs, ptok, pw, H, out, FFC, c, wfull);
    }
}

// Round 3
// 1412.125 us; speedup vs baseline: 1.1461x; 1.0398x over previous
//
#include <hip/hip_runtime.h>
#include <cstdint>
#include <math.h>

#define T_TOK 8192
#define DM 1024
#define DFF 4096
#define NE 8

typedef __attribute__((ext_vector_type(8))) short short8;
typedef __attribute__((ext_vector_type(4))) float f32x4;

#define GLDS16(g, l) __builtin_amdgcn_global_load_lds( \
    (const __attribute__((address_space(1))) void*)(g), \
    (__attribute__((address_space(3))) void*)(l), 16, 0, 0)

static __device__ __forceinline__ unsigned short f2bf(float f) {
    union { float f; unsigned int u; } v; v.f = f;
    unsigned int r = (v.u + 0x7FFFu + ((v.u >> 16) & 1u)) >> 16;
    return (unsigned short)r;
}

// ---------------- fp32 -> bf16 converters ----------------
__global__ __launch_bounds__(256) void conv_flat(const float* __restrict__ src,
                                                 unsigned short* __restrict__ dst,
                                                 long long n)
{
    long long i = ((long long)blockIdx.x * 256 + threadIdx.x) * 4;
    if (i >= n) return;
    const float4 v = *(const float4*)(src + i);
    uint2 u;
    u.x = (unsigned)f2bf(v.x) | ((unsigned)f2bf(v.y) << 16);
    u.y = (unsigned)f2bf(v.z) | ((unsigned)f2bf(v.w) << 16);
    *(uint2*)(dst + i) = u;
}

__global__ __launch_bounds__(256) void conv_rows(const float* __restrict__ src,
                                                 unsigned short* __restrict__ dst,
                                                 long long src_off, long long src_stride,
                                                 int ncols)
{
    long long row = blockIdx.y;
    int c = (blockIdx.x * 256 + threadIdx.x) * 4;
    if (c >= ncols) return;
    const float4 v = *(const float4*)(src + src_off + row * src_stride + c);
    uint2 u;
    u.x = (unsigned)f2bf(v.x) | ((unsigned)f2bf(v.y) << 16);
    u.y = (unsigned)f2bf(v.z) | ((unsigned)f2bf(v.w) << 16);
    *(uint2*)(dst + row * (long long)ncols + c) = u;
}

// ---------------- Router ----------------
__global__ __launch_bounds__(256) void router_kernel(
    const float* __restrict__ x, const float* __restrict__ gw,
    int* __restrict__ counts, float* __restrict__ imp,
    int* __restrict__ ptok, float* __restrict__ pw)
{
    __shared__ float4 sgw[NE * 256];
    __shared__ float simp[NE];
    const int tid = threadIdx.x;
    #pragma unroll
    for (int j = 0; j < 8; ++j) sgw[tid + j * 256] = ((const float4*)gw)[tid + j * 256];
    if (tid < NE) simp[tid] = 0.f;
    __syncthreads();

    const int wid = tid >> 6, lane = tid & 63;
    const int t = blockIdx.x * 4 + wid;
    float acc[NE];
    #pragma unroll
    for (int e = 0; e < NE; ++e) acc[e] = 0.f;
    const float4* xr = (const float4*)(x + (size_t)t * DM);
    #pragma unroll
    for (int j = 0; j < 4; ++j) {
        int idx = lane + j * 64;
        float4 xv = xr[idx];
        #pragma unroll
        for (int e = 0; e < NE; ++e) {
            float4 g = sgw[e * 256 + idx];
            acc[e] += xv.x * g.x + xv.y * g.y + xv.z * g.z + xv.w * g.w;
        }
    }
    #pragma unroll
    for (int off = 32; off; off >>= 1) {
        #pragma unroll
        for (int e = 0; e < NE; ++e) acc[e] += __shfl_xor(acc[e], off);
    }
    if (lane == 0) {
        float m = acc[0];
        #pragma unroll
        for (int e = 1; e < NE; ++e) m = fmaxf(m, acc[e]);
        float p[NE], s = 0.f;
        #pragma unroll
        for (int e = 0; e < NE; ++e) { p[e] = expf(acc[e] - m); s += p[e]; }
        float inv = 1.f / s;
        #pragma unroll
        for (int e = 0; e < NE; ++e) { p[e] *= inv; atomicAdd(&simp[e], p[e]); }
        int i0 = 0;
        #pragma unroll
        for (int e = 1; e < NE; ++e) if (p[e] > p[i0]) i0 = e;
        int i1 = (i0 == 0) ? 1 : 0;
        #pragma unroll
        for (int e = 0; e < NE; ++e) if (e != i0 && p[e] > p[i1]) i1 = e;
        float v0 = p[i0], v1 = p[i1], wsum = v0 + v1;
        int s0 = atomicAdd(&counts[i0], 1);
        ptok[i0 * T_TOK + s0] = t; pw[i0 * T_TOK + s0] = v0 / wsum;
        int s1 = atomicAdd(&counts[i1], 1);
        ptok[i1 * T_TOK + s1] = t; pw[i1 * T_TOK + s1] = v1 / wsum;
    }
    __syncthreads();
    if (tid < NE) atomicAdd(&imp[tid], simp[tid]);
}

__global__ void finalize_kernel(const int* __restrict__ counts,
                                const float* __restrict__ imp,
                                int* __restrict__ offs, float* __restrict__ aux_out)
{
    if (threadIdx.x == 0 && blockIdx.x == 0) {
        int o = 0; float aux = 0.f;
        for (int e = 0; e < NE; ++e) {
            offs[e] = o; o += counts[e];
            aux += (imp[e] / (float)T_TOK) * ((float)counts[e] / (float)(T_TOK * 2));
        }
        offs[NE] = o;
        *aux_out = (float)NE * aux;
    }
}

// ---------------- Grouped GEMM (B^T), 128x128, BK=64, dbuf LDS + prefetch + T2 swizzle ----------------
// EPI==0: H[pair, f] = gelu(gather(xb) @ w1b[e]^T + b1)   (K = DM,  N = FFC chunk)
// EPI==1: out[tok,d] += w_pair * (H @ w2b[e]^T + b2)      (K = FFC, N = DM)
template<int EPI>
__global__ __launch_bounds__(256) void gemm_bt(
    const unsigned short* __restrict__ A,
    const unsigned short* __restrict__ W,
    const float* __restrict__ bias,
    const int* __restrict__ counts, const int* __restrict__ offs,
    const int* __restrict__ ptok, const float* __restrict__ pw,
    unsigned short* __restrict__ Hout, float* __restrict__ out,
    int FFC, int cch, int wfull)
{
    const int e = blockIdx.z;
    const int n_e = counts[e];
    const int m0 = blockIdx.x * 128;
    if (m0 >= n_e) return;
    const int nt = blockIdx.y;
    const int KD = (EPI == 0) ? DM : FFC;
    const int hbase = offs[e];

    // double-buffered LDS, 64 KB total
    __shared__ unsigned short lA[2][128 * 64];
    __shared__ unsigned short lB[2][128 * 64];

    const int tid = threadIdx.x, lane = tid & 63, wid = tid >> 6;
    const int msub = (wid & 1) * 64, nsub = (wid >> 1) * 64;
    const int hi = lane >> 4, lo = lane & 15;

    int wrow0; long long wstride, wcol0;
    if (EPI == 0) {
        wrow0 = e * (wfull ? DFF : FFC) + (wfull ? cch * FFC : 0) + nt * 128;
        wstride = DM; wcol0 = 0;
    } else {
        wrow0 = e * DM + nt * 128;
        wstride = (wfull ? DFF : FFC); wcol0 = (wfull ? (long long)cch * FFC : 0);
    }

    // Per-thread global source addresses, column pre-swizzled (inverse of read swizzle)
    // so linear global_load_lds dest + XOR'd ds_read = identity (rule #21).
    const unsigned short* aaddr[4];
    const unsigned short* baddr[4];
    #pragma unroll
    for (int j = 0; j < 4; ++j) {
        int li = tid + j * 256;
        int r = li >> 3;
        int scol = ((li & 7) ^ (r & 7)) * 8;   // swizzled 16B slot within 128B row
        long long arow;
        if (EPI == 0) {
            int m = m0 + r;
            int tok = ptok[e * T_TOK + (m < n_e ? m : 0)];
            arow = (long long)tok * DM;
        } else {
            int m = m0 + r;
            arow = (long long)(hbase + (m < n_e ? m : 0)) * FFC;
        }
        aaddr[j] = A + arow + scol;
        baddr[j] = W + (long long)(wrow0 + r) * wstride + wcol0 + scol;
    }

    f32x4 acc[4][4];
    #pragma unroll
    for (int i = 0; i < 4; ++i)
        #pragma unroll
        for (int j = 0; j < 4; ++j) acc[i][j] = (f32x4)0.f;

    const int NT = KD / 64;

    // prologue: stage tile 0 into buf 0
    #pragma unroll
    for (int j = 0; j < 4; ++j) {
        GLDS16(aaddr[j], &lA[0][(tid + j * 256) * 8]);
        GLDS16(baddr[j], &lB[0][(tid + j * 256) * 8]);
    }
    __syncthreads();

    for (int t = 0; t < NT; ++t) {
        const int cur = t & 1;
        if (t + 1 < NT) {
            const int nxt = cur ^ 1;
            const long long k0 = (long long)(t + 1) * 64;
            #pragma unroll
            for (int j = 0; j < 4; ++j) {
                GLDS16(aaddr[j] + k0, &lA[nxt][(tid + j * 256) * 8]);
                GLDS16(baddr[j] + k0, &lB[nxt][(tid + j * 256) * 8]);
            }
        }
        #pragma unroll
        for (int kk = 0; kk < 2; ++kk) {
            const int soff = ((kk * 4 + hi) ^ (lo & 7)) * 8;  // swizzled read slot
            short8 af[4], bf[4];
            #pragma unroll
            for (int i = 0; i < 4; ++i) {
                af[i] = *(const short8*)(&lA[cur][(msub + i * 16 + lo) * 64 + soff]);
                bf[i] = *(const short8*)(&lB[cur][(nsub + i * 16 + lo) * 64 + soff]);
            }
            #pragma unroll
            for (int mi = 0; mi < 4; ++mi)
                #pragma unroll
                for (int nj = 0; nj < 4; ++nj)
                    acc[mi][nj] = __builtin_amdgcn_mfma_f32_16x16x32_bf16(af[mi], bf[nj], acc[mi][nj], 0, 0, 0);
        }
        __syncthreads();  // drains S(t+1) (vmcnt 0) + closes reads on buf[cur]
    }

    const int rbase = hi * 4, cidx = lo;
    if (EPI == 0) {
        #pragma unroll
        for (int mi = 0; mi < 4; ++mi) {
            #pragma unroll
            for (int r = 0; r < 4; ++r) {
                int m = m0 + msub + mi * 16 + rbase + r;
                if (m >= n_e) continue;
                long long hrow = (long long)(hbase + m) * FFC;
                #pragma unroll
                for (int nj = 0; nj < 4; ++nj) {
                    int f = nt * 128 + nsub + nj * 16 + cidx;
                    float v = acc[mi][nj][r] + bias[e * DFF + cch * FFC + f];
                    float g = 0.5f * v * (1.f + erff(v * 0.70710678118654752f));
                    Hout[hrow + f] = f2bf(g);
                }
            }
        }
    } else {
        #pragma unroll
        for (int mi = 0; mi < 4; ++mi) {
            #pragma unroll
            for (int r = 0; r < 4; ++r) {
                int m = m0 + msub + mi * 16 + rbase + r;
                if (m >= n_e) continue;
                int pidx = e * T_TOK + m;
                int tok = ptok[pidx];
                float wgt = pw[pidx];
                float* orow = out + (long long)tok * DM;
                #pragma unroll
                for (int nj = 0; nj < 4; ++nj) {
                    int d = nt * 128 + nsub + nj * 16 + cidx;
                    float v = acc[mi][nj][r];
                    if (cch == 0) v += bias[e * DM + d];
                    atomicAdd(&orow[d], wgt * v);
                }
            }
        }
    }
}

extern "C" void kernel_launch(void* const* d_in, const int* in_sizes, int n_in,
                              void* d_out, int out_size, void* d_ws, size_t ws_size,
                              hipStream_t stream)
{
    const float* x  = (const float*)d_in[0];
    const float* gw = (const float*)d_in[1];
    const float* w1 = (const float*)d_in[2];
    const float* b1 = (const float*)d_in[3];
    const float* w2 = (const float*)d_in[4];
    const float* b2 = (const float*)d_in[5];
    float* out = (float*)d_out;

    char* ws = (char*)d_ws;
    int*   counts = (int*)ws;
    float* imp    = (float*)(ws + 64);
    int*   offs   = (int*)(ws + 128);
    int*   ptok   = (int*)(ws + 256);
    float* pw     = (float*)(ws + 256 + (size_t)NE * T_TOK * 4);
    size_t cur = 256 + (size_t)NE * T_TOK * 8;
    cur = (cur + 511) & ~(size_t)511;

    unsigned short* xb = (unsigned short*)(ws + cur);
    cur += (size_t)T_TOK * DM * 2;

    const size_t wfull_bytes = (size_t)NE * DFF * DM * 2;
    const size_t hrow_total  = 2 * (size_t)T_TOK;

    int FFC = 0, wfull = 0;
    unsigned short *w1b = nullptr, *w2b = nullptr, *H = nullptr;
    for (int f = DFF; f >= 512; f >>= 1) {
        size_t need = cur + 2 * wfull_bytes + hrow_total * (size_t)f * 2;
        if (need <= ws_size) { FFC = f; wfull = 1; break; }
    }
    if (wfull) {
        w1b = (unsigned short*)(ws + cur); cur += wfull_bytes;
        w2b = (unsigned short*)(ws + cur); cur += wfull_bytes;
        H   = (unsigned short*)(ws + cur);
    } else {
        for (int f = 1024; f >= 128; f >>= 1) {
            size_t wc = (size_t)NE * f * DM * 2;
            size_t need = cur + 2 * wc + hrow_total * (size_t)f * 2;
            if (need <= ws_size) { FFC = f; break; }
        }
        if (FFC == 0) return;
        size_t wc = (size_t)NE * FFC * DM * 2;
        w1b = (unsigned short*)(ws + cur); cur += wc;
        w2b = (unsigned short*)(ws + cur); cur += wc;
        H   = (unsigned short*)(ws + cur);
    }

    hipMemsetAsync(ws, 0, 256, stream);
    hipMemsetAsync(d_out, 0, (size_t)out_size * 4, stream);

    router_kernel<<<T_TOK / 4, 256, 0, stream>>>(x, gw, counts, imp, ptok, pw);
    finalize_kernel<<<1, 64, 0, stream>>>(counts, imp, offs, out + (size_t)out_size - 1);

    {
        long long n = (long long)T_TOK * DM;
        conv_flat<<<(unsigned)(n / 1024), 256, 0, stream>>>(x, xb, n);
    }
    if (wfull) {
        long long n = (long long)NE * DFF * DM;
        conv_flat<<<(unsigned)(n / 1024), 256, 0, stream>>>(w1, w1b, n);
        conv_flat<<<(unsigned)(n / 1024), 256, 0, stream>>>(w2, w2b, n);
    }

    const int NCH = DFF / FFC;
    for (int c = 0; c < NCH; ++c) {
        if (!wfull) {
            dim3 gc1((unsigned)((long long)FFC * DM / 1024), NE);
            conv_rows<<<gc1, 256, 0, stream>>>(w1, w1b,
                (long long)c * FFC * DM, (long long)DFF * DM, FFC * DM);
            dim3 gc2((unsigned)((FFC + 1023) / 1024), NE * DM);
            conv_rows<<<gc2, 256, 0, stream>>>(w2, w2b,
                (long long)c * FFC, (long long)DFF, FFC);
        }
        dim3 g1(T_TOK / 128, FFC / 128, NE);
        gemm_bt<0><<<g1, 256, 0, stream>>>(xb, w1b, b1, counts, offs, ptok, pw, H, out, FFC, c, wfull);
        dim3 g2(T_TOK / 128, DM / 128, NE);
        gemm_bt<1><<<g2, 256, 0, stream>>>(H, w2b, b2, counts, offs, ptok, pw, H, out, FFC, c, wfull);
    }
}